// Round 6
// baseline (653.667 us; speedup 1.0000x reference)
//
#include <hip/hip_runtime.h>
#include <hip/hip_bf16.h>
#include <stdint.h>

// PLE layer: T=3 tasks, B=16384 rows, I=1024, O=512, 4 shared + 2 task experts, 6 gates.
// Round 5 (resubmit; prior round was an infra timeout): keep proven T2-swizzled 2-barrier
// MFMA core; restructure kernels to kill redundant traffic: fused cvt+gates, task0 fused
// with shared experts (same A=x0), tasks 1/2 with both experts paired in one K-loop.

#define TTASKS 3
#define BROWS  16384
#define KDIM   1024
#define ODIM   512
#define NGATE  6

typedef __attribute__((ext_vector_type(8))) __bf16 bf16x8;
typedef __attribute__((ext_vector_type(4))) float  f32x4;

// ---------------- ws layout (same offsets as rounds 2-4, proven) ----------------
#define XB_OFF 0
#define WT_OFF 100663296UL
#define GT_OFF 111149056UL
#define SH_OFF 112328704UL

#define MFMA_(a, bb, c) __builtin_amdgcn_mfma_f32_16x16x32_bf16(a, bb, c, 0, 0, 0)

// ---------------- cvt inputs f32 -> bf16 AND gates, one wave per row ----------------
__global__ __launch_bounds__(256) void cvt_gates(const float* __restrict__ x,
                                                 __bf16* __restrict__ xb,
                                                 const float* __restrict__ gW,
                                                 const float* __restrict__ gb,
                                                 float* __restrict__ gates) {
  const int w = blockIdx.x * 4 + (threadIdx.x >> 6);   // row 0..49151
  const int lane = threadIdx.x & 63;
  const int t = w >> 14;
  const float* xr = x + (size_t)w * KDIM;
  const float* gw = gW + (size_t)t * KDIM * NGATE;

  // load 16 consecutive f32 per lane, convert, store 2x bf16x8
  const int k0 = lane * 16;
  float4 f[4];
#pragma unroll
  for (int i = 0; i < 4; ++i) f[i] = *(const float4*)(xr + k0 + i * 4);
  bf16x8 o0 = { (__bf16)f[0].x, (__bf16)f[0].y, (__bf16)f[0].z, (__bf16)f[0].w,
                (__bf16)f[1].x, (__bf16)f[1].y, (__bf16)f[1].z, (__bf16)f[1].w };
  bf16x8 o1 = { (__bf16)f[2].x, (__bf16)f[2].y, (__bf16)f[2].z, (__bf16)f[2].w,
                (__bf16)f[3].x, (__bf16)f[3].y, (__bf16)f[3].z, (__bf16)f[3].w };
  *(bf16x8*)(xb + (size_t)w * KDIM + k0)     = o0;
  *(bf16x8*)(xb + (size_t)w * KDIM + k0 + 8) = o1;

  // gate dots from exact f32 values (gw rows are 24B -> 3x float2, 8B-aligned)
  float d[NGATE] = {0.f, 0.f, 0.f, 0.f, 0.f, 0.f};
#pragma unroll
  for (int kk = 0; kk < 16; ++kk) {
    float xf = ((const float*)f)[kk];
    const float* gr = gw + (size_t)(k0 + kk) * NGATE;
    float2 ga = *(const float2*)(gr);
    float2 gbv = *(const float2*)(gr + 2);
    float2 gc = *(const float2*)(gr + 4);
    d[0] += xf * ga.x;  d[1] += xf * ga.y;
    d[2] += xf * gbv.x; d[3] += xf * gbv.y;
    d[4] += xf * gc.x;  d[5] += xf * gc.y;
  }
#pragma unroll
  for (int j = 0; j < NGATE; ++j) {
#pragma unroll
    for (int off = 32; off > 0; off >>= 1) d[j] += __shfl_xor(d[j], off, 64);
    d[j] += gb[t * NGATE + j];
  }
  float m = d[0];
#pragma unroll
  for (int j = 1; j < NGATE; ++j) m = fmaxf(m, d[j]);
  float s = 0.f;
#pragma unroll
  for (int j = 0; j < NGATE; ++j) { d[j] = expf(d[j] - m); s += d[j]; }
  float inv = 1.f / s;
  if (lane < NGATE) {
    float v = d[0];
#pragma unroll
    for (int j = 1; j < NGATE; ++j) v = (lane == j) ? d[j] : v;
    gates[(size_t)w * NGATE + lane] = v * inv;
  }
}

// ---------------- cvt + transpose weights: W[k][o] f32 -> wT[o][k] bf16 ----------------
__global__ __launch_bounds__(256) void cvt_weights(const float* __restrict__ shW,
                                                   const float* __restrict__ tkW,
                                                   __bf16* __restrict__ wT) {
  int s = blockIdx.z;
  const float* src = (s < 4) ? (shW + (size_t)s * KDIM * ODIM)
                             : (tkW + (size_t)(s - 4) * KDIM * ODIM);
  int o   = blockIdx.x * 64 + (threadIdx.x & 63);
  int sub = threadIdx.x >> 6;
#pragma unroll
  for (int kk = 0; kk < 2; ++kk) {
    int k0 = blockIdx.y * 64 + (sub * 2 + kk) * 8;
    bf16x8 v;
#pragma unroll
    for (int i = 0; i < 8; ++i)
      v[i] = (__bf16)src[(size_t)(k0 + i) * ODIM + o];
    *(bf16x8*)(wT + ((size_t)s * ODIM + o) * KDIM + k0) = v;
  }
}

// ---------------- T2-swizzled staging of one [128][64] bf16 tile ----------------
// LDS slot (r, c) holds global chunk c^(r&7); read applies the same XOR (involution).
__device__ __forceinline__ void stage_tile(const __bf16* __restrict__ g,
                                           __bf16* lds, int tid, int wv) {
#pragma unroll
  for (int it = 0; it < 4; ++it) {
    const int idx = it * 256 + tid;            // 0..1023
    const int r   = idx >> 3;                  // row 0..127
    const int cs  = (idx & 7) ^ (r & 7);       // pre-swizzled 16B chunk
    __builtin_amdgcn_global_load_lds(
        (const __attribute__((address_space(1))) void*)(g + (size_t)r * KDIM + cs * 8),
        (__attribute__((address_space(3))) void*)(lds + (it * 256 + wv * 64) * 8), 16, 0, 0);
  }
}

// ---------------- single-expert 128x128xK core (m97-style, swizzled) ----------------
__device__ __forceinline__ void gemm_128(const __bf16* __restrict__ Ap,
                                         const __bf16* __restrict__ Bp,
                                         __bf16* As, __bf16* Bs,
                                         f32x4 acc[4][4]) {
  const int tid = threadIdx.x, lane = tid & 63, wv = tid >> 6;
  const int wm = wv >> 1, wn = wv & 1;
  const int lr = lane & 15, lg = lane >> 4, x7 = lr & 7;

  for (int kt = 0; kt < 16; ++kt) {
    stage_tile(Ap + kt * 64, As, tid, wv);
    stage_tile(Bp + kt * 64, Bs, tid, wv);
    __syncthreads();
    const __bf16* aB = As + (wm * 64 + lr) * 64;
    const __bf16* bB = Bs + (wn * 64 + lr) * 64;
#pragma unroll
    for (int ks = 0; ks < 2; ++ks) {
      const int xo = ((ks * 4 + lg) ^ x7) * 8;
      bf16x8 af[4], bf[4];
#pragma unroll
      for (int mi = 0; mi < 4; ++mi) af[mi] = *(const bf16x8*)(aB + mi * 16 * 64 + xo);
#pragma unroll
      for (int ni = 0; ni < 4; ++ni) bf[ni] = *(const bf16x8*)(bB + ni * 16 * 64 + xo);
#pragma unroll
      for (int mi = 0; mi < 4; ++mi)
#pragma unroll
        for (int ni = 0; ni < 4; ++ni)
          acc[mi][ni] = MFMA_(af[mi], bf[ni], acc[mi][ni]);
    }
    __syncthreads();
  }
}

// ---------------- task 0 + 4 shared experts (all A = x0): 6 GEMMs, fused combine ----
__global__ __launch_bounds__(256, 2) void task0_shared(const __bf16* __restrict__ xb0,
                                                       const __bf16* __restrict__ wT,
                                                       const float* __restrict__ shb,
                                                       const float* __restrict__ tkb,
                                                       const float* __restrict__ gates,
                                                       __bf16* __restrict__ shOut,
                                                       float* __restrict__ out) {
  __shared__ __align__(16) __bf16 As[128 * 64], Bs[128 * 64];
  const int rowBase = blockIdx.x * 128, colBase = blockIdx.y * 128;
  const int tid = threadIdx.x, lane = tid & 63, wv = tid >> 6;
  const int wm = wv >> 1, wn = wv & 1, lr = lane & 15, lg = lane >> 4;
  const __bf16* Ap = xb0 + (size_t)rowBase * KDIM;

  float outv[4][4][4];
#pragma unroll
  for (int mi = 0; mi < 4; ++mi)
#pragma unroll
    for (int ni = 0; ni < 4; ++ni)
#pragma unroll
      for (int r = 0; r < 4; ++r) outv[mi][ni][r] = 0.f;

#pragma unroll 1
  for (int e = 0; e < 6; ++e) {   // wT index e: shared 0..3, task0 experts 4,5
    f32x4 acc[4][4];
    f32x4 z = {0.f, 0.f, 0.f, 0.f};
#pragma unroll
    for (int mi = 0; mi < 4; ++mi)
#pragma unroll
      for (int ni = 0; ni < 4; ++ni) acc[mi][ni] = z;

    gemm_128(Ap, wT + ((size_t)e * ODIM + colBase) * KDIM, As, Bs, acc);

    const float* bias_p = (e < 4) ? (shb + e * ODIM) : (tkb + (e - 4) * ODIM);
#pragma unroll
    for (int ni = 0; ni < 4; ++ni) {
      int col = colBase + wn * 64 + ni * 16 + lr;
      float bias = bias_p[col];
#pragma unroll
      for (int mi = 0; mi < 4; ++mi)
#pragma unroll
        for (int r = 0; r < 4; ++r) {
          int row = rowBase + wm * 64 + mi * 16 + lg * 4 + r;
          float v = fmaxf(acc[mi][ni][r] + bias, 0.f);
          if (e < 4)
            shOut[((size_t)e * BROWS + row) * ODIM + col] = (__bf16)v;
          outv[mi][ni][r] += gates[(size_t)row * NGATE + e] * v;
        }
    }
  }

#pragma unroll
  for (int ni = 0; ni < 4; ++ni) {
    int col = colBase + wn * 64 + ni * 16 + lr;
#pragma unroll
    for (int mi = 0; mi < 4; ++mi)
#pragma unroll
      for (int r = 0; r < 4; ++r) {
        int row = rowBase + wm * 64 + mi * 16 + lg * 4 + r;
        out[(size_t)row * ODIM + col] = outv[mi][ni][r];
      }
  }
}

// ---------------- tasks 1,2: both experts paired in ONE K-loop + combine ----------
__global__ __launch_bounds__(256, 2) void task12_pair(const __bf16* __restrict__ xb,
                                                      const __bf16* __restrict__ wT,
                                                      const float* __restrict__ tkb,
                                                      const float* __restrict__ gates,
                                                      const __bf16* __restrict__ shOut,
                                                      float* __restrict__ out) {
  __shared__ __align__(16) __bf16 As[128 * 64], Bs0[128 * 64], Bs1[128 * 64];
  const int t = 1 + blockIdx.z;
  const int rowBase = blockIdx.x * 128, colBase = blockIdx.y * 128;
  const int tid = threadIdx.x, lane = tid & 63, wv = tid >> 6;
  const int wm = wv >> 1, wn = wv & 1, lr = lane & 15, lg = lane >> 4, x7 = lr & 7;
  const size_t NB = (size_t)BROWS * ODIM;

  const __bf16* Ap  = xb + ((size_t)t * BROWS + rowBase) * KDIM;
  const __bf16* Bp0 = wT + ((size_t)(4 + t * 2) * ODIM + colBase) * KDIM;
  const __bf16* Bp1 = wT + ((size_t)(4 + t * 2 + 1) * ODIM + colBase) * KDIM;

  f32x4 acc0[4][4], acc1[4][4];
  f32x4 z = {0.f, 0.f, 0.f, 0.f};
#pragma unroll
  for (int mi = 0; mi < 4; ++mi)
#pragma unroll
    for (int ni = 0; ni < 4; ++ni) { acc0[mi][ni] = z; acc1[mi][ni] = z; }

  for (int kt = 0; kt < 16; ++kt) {
    stage_tile(Ap  + kt * 64, As,  tid, wv);
    stage_tile(Bp0 + kt * 64, Bs0, tid, wv);
    stage_tile(Bp1 + kt * 64, Bs1, tid, wv);
    __syncthreads();
    const __bf16* aB  = As  + (wm * 64 + lr) * 64;
    const __bf16* bB0 = Bs0 + (wn * 64 + lr) * 64;
    const __bf16* bB1 = Bs1 + (wn * 64 + lr) * 64;
#pragma unroll
    for (int ks = 0; ks < 2; ++ks) {
      const int xo = ((ks * 4 + lg) ^ x7) * 8;
      bf16x8 af[4], bf0[4], bf1[4];
#pragma unroll
      for (int mi = 0; mi < 4; ++mi) af[mi]  = *(const bf16x8*)(aB  + mi * 16 * 64 + xo);
#pragma unroll
      for (int ni = 0; ni < 4; ++ni) bf0[ni] = *(const bf16x8*)(bB0 + ni * 16 * 64 + xo);
#pragma unroll
      for (int ni = 0; ni < 4; ++ni) bf1[ni] = *(const bf16x8*)(bB1 + ni * 16 * 64 + xo);
#pragma unroll
      for (int mi = 0; mi < 4; ++mi)
#pragma unroll
        for (int ni = 0; ni < 4; ++ni) {
          acc0[mi][ni] = MFMA_(af[mi], bf0[ni], acc0[mi][ni]);
          acc1[mi][ni] = MFMA_(af[mi], bf1[ni], acc1[mi][ni]);
        }
    }
    __syncthreads();
  }

#pragma unroll
  for (int mi = 0; mi < 4; ++mi)
#pragma unroll
    for (int r = 0; r < 4; ++r) {
      int row = rowBase + wm * 64 + mi * 16 + lg * 4 + r;
      const float* gp = gates + ((size_t)t * BROWS + row) * NGATE;
      float g0 = gp[0], g1 = gp[1], g2 = gp[2], g3 = gp[3], g4 = gp[4], g5 = gp[5];
#pragma unroll
      for (int ni = 0; ni < 4; ++ni) {
        int col = colBase + wn * 64 + ni * 16 + lr;
        size_t rc = (size_t)row * ODIM + col;
        float s = g0 * (float)shOut[rc] + g1 * (float)shOut[NB + rc] +
                  g2 * (float)shOut[2 * NB + rc] + g3 * (float)shOut[3 * NB + rc];
        s += g4 * fmaxf(acc0[mi][ni][r] + tkb[(t * 2) * ODIM + col], 0.f);
        s += g5 * fmaxf(acc1[mi][ni][r] + tkb[(t * 2 + 1) * ODIM + col], 0.f);
        out[((size_t)t * BROWS + row) * ODIM + col] = s;
      }
    }
}

extern "C" void kernel_launch(void* const* d_in, const int* in_sizes, int n_in,
                              void* d_out, int out_size, void* d_ws, size_t ws_size,
                              hipStream_t stream) {
  const float* x   = (const float*)d_in[0];
  const float* shW = (const float*)d_in[1];
  const float* shb = (const float*)d_in[2];
  const float* tkW = (const float*)d_in[3];
  const float* tkb = (const float*)d_in[4];
  const float* gW  = (const float*)d_in[5];
  const float* gb  = (const float*)d_in[6];
  float* out = (float*)d_out;
  (void)in_sizes; (void)n_in; (void)out_size; (void)ws_size;

  char* ws = (char*)d_ws;
  __bf16* xb    = (__bf16*)(ws + XB_OFF);
  __bf16* wT    = (__bf16*)(ws + WT_OFF);
  float*  gates = (float*) (ws + GT_OFF);
  __bf16* shOut = (__bf16*)(ws + SH_OFF);

  cvt_gates  <<<dim3((TTASKS * BROWS) / 4), 256, 0, stream>>>(x, xb, gW, gb, gates);
  cvt_weights<<<dim3(8, 16, 10), 256, 0, stream>>>(shW, tkW, wT);

  task0_shared<<<dim3(BROWS / 128, ODIM / 128), 256, 0, stream>>>(xb, wT, shb, tkb,
                                                                  gates, shOut, out);
  task12_pair <<<dim3(BROWS / 128, ODIM / 128, 2), 256, 0, stream>>>(xb, wT, tkb, gates,
                                                                     shOut, out);
}

// Round 7
// 544.939 us; speedup vs baseline: 1.1995x; 1.1995x over previous
//
#include <hip/hip_runtime.h>
#include <hip/hip_bf16.h>
#include <stdint.h>

// PLE layer: T=3 tasks, B=16384 rows, I=1024, O=512, 4 shared + 2 task experts, 6 gates.
// Round 7: single change vs round 6 — cvt_gates rewritten for coalesced IO + LDS-staged gW
// (round 6 profile: cvt_gates was 196us at 1TB/s, VMEM-transaction-bound). GEMM kernels
// byte-identical to round 6 (T2-swizzled 2-barrier core, task0+shared fused, task12 paired).

#define TTASKS 3
#define BROWS  16384
#define KDIM   1024
#define ODIM   512
#define NGATE  6

typedef __attribute__((ext_vector_type(8))) __bf16 bf16x8;
typedef __attribute__((ext_vector_type(4))) float  f32x4;

// ---------------- ws layout (same offsets as rounds 2-6, proven) ----------------
#define XB_OFF 0
#define WT_OFF 100663296UL
#define GT_OFF 111149056UL
#define SH_OFF 112328704UL

#define MFMA_(a, bb, c) __builtin_amdgcn_mfma_f32_16x16x32_bf16(a, bb, c, 0, 0, 0)

// ---------------- cvt inputs f32 -> bf16 AND gates; coalesced + LDS gW ----------------
// One block = 4 rows (one per wave), all in the same task. gW[t] (24 KB) staged in LDS.
__global__ __launch_bounds__(256) void cvt_gates(const float* __restrict__ x,
                                                 __bf16* __restrict__ xb,
                                                 const float* __restrict__ gW,
                                                 const float* __restrict__ gb,
                                                 float* __restrict__ gates) {
  __shared__ __align__(16) float gwl[KDIM * NGATE];   // 24 KB
  const int tid = threadIdx.x;
  const int w0 = blockIdx.x * 4;                      // 4 rows per block, same task
  const int t  = w0 >> 14;

  // stage gW[t] -> LDS: 6 coalesced float4 loads per thread (1536 float4 total)
  const float4* gsrc = (const float4*)(gW + (size_t)t * KDIM * NGATE);
  float4* gdst = (float4*)gwl;
#pragma unroll
  for (int i = 0; i < 6; ++i) gdst[tid + i * 256] = gsrc[tid + i * 256];
  __syncthreads();

  const int wvi = tid >> 6, lane = tid & 63;
  const int w = w0 + wvi;
  const float* xr = x + (size_t)w * KDIM;
  __bf16* xw = xb + (size_t)w * KDIM;

  float d[NGATE] = {0.f, 0.f, 0.f, 0.f, 0.f, 0.f};
#pragma unroll
  for (int i = 0; i < 16; ++i) {
    const int k = i * 64 + lane;          // lane-stride 1: fully coalesced
    float xf = xr[k];                     // 256 B/wave per instr
    xw[k] = (__bf16)xf;                   // 128 B/wave per instr
    const float* gr = gwl + k * NGATE;    // lane-stride 24 B -> 4-way LDS conflict (cheap)
    float2 g01 = *(const float2*)(gr);
    float2 g23 = *(const float2*)(gr + 2);
    float2 g45 = *(const float2*)(gr + 4);
    d[0] += xf * g01.x;  d[1] += xf * g01.y;
    d[2] += xf * g23.x;  d[3] += xf * g23.y;
    d[4] += xf * g45.x;  d[5] += xf * g45.y;
  }
#pragma unroll
  for (int j = 0; j < NGATE; ++j) {
#pragma unroll
    for (int off = 32; off > 0; off >>= 1) d[j] += __shfl_xor(d[j], off, 64);
    d[j] += gb[t * NGATE + j];
  }
  float m = d[0];
#pragma unroll
  for (int j = 1; j < NGATE; ++j) m = fmaxf(m, d[j]);
  float s = 0.f;
#pragma unroll
  for (int j = 0; j < NGATE; ++j) { d[j] = expf(d[j] - m); s += d[j]; }
  float inv = 1.f / s;
  if (lane < NGATE) {
    float v = d[0];
#pragma unroll
    for (int j = 1; j < NGATE; ++j) v = (lane == j) ? d[j] : v;
    gates[(size_t)w * NGATE + lane] = v * inv;
  }
}

// ---------------- cvt + transpose weights: W[k][o] f32 -> wT[o][k] bf16 ----------------
__global__ __launch_bounds__(256) void cvt_weights(const float* __restrict__ shW,
                                                   const float* __restrict__ tkW,
                                                   __bf16* __restrict__ wT) {
  int s = blockIdx.z;
  const float* src = (s < 4) ? (shW + (size_t)s * KDIM * ODIM)
                             : (tkW + (size_t)(s - 4) * KDIM * ODIM);
  int o   = blockIdx.x * 64 + (threadIdx.x & 63);
  int sub = threadIdx.x >> 6;
#pragma unroll
  for (int kk = 0; kk < 2; ++kk) {
    int k0 = blockIdx.y * 64 + (sub * 2 + kk) * 8;
    bf16x8 v;
#pragma unroll
    for (int i = 0; i < 8; ++i)
      v[i] = (__bf16)src[(size_t)(k0 + i) * ODIM + o];
    *(bf16x8*)(wT + ((size_t)s * ODIM + o) * KDIM + k0) = v;
  }
}

// ---------------- T2-swizzled staging of one [128][64] bf16 tile ----------------
// LDS slot (r, c) holds global chunk c^(r&7); read applies the same XOR (involution).
__device__ __forceinline__ void stage_tile(const __bf16* __restrict__ g,
                                           __bf16* lds, int tid, int wv) {
#pragma unroll
  for (int it = 0; it < 4; ++it) {
    const int idx = it * 256 + tid;            // 0..1023
    const int r   = idx >> 3;                  // row 0..127
    const int cs  = (idx & 7) ^ (r & 7);       // pre-swizzled 16B chunk
    __builtin_amdgcn_global_load_lds(
        (const __attribute__((address_space(1))) void*)(g + (size_t)r * KDIM + cs * 8),
        (__attribute__((address_space(3))) void*)(lds + (it * 256 + wv * 64) * 8), 16, 0, 0);
  }
}

// ---------------- single-expert 128x128xK core (m97-style, swizzled) ----------------
__device__ __forceinline__ void gemm_128(const __bf16* __restrict__ Ap,
                                         const __bf16* __restrict__ Bp,
                                         __bf16* As, __bf16* Bs,
                                         f32x4 acc[4][4]) {
  const int tid = threadIdx.x, lane = tid & 63, wv = tid >> 6;
  const int wm = wv >> 1, wn = wv & 1;
  const int lr = lane & 15, lg = lane >> 4, x7 = lr & 7;

  for (int kt = 0; kt < 16; ++kt) {
    stage_tile(Ap + kt * 64, As, tid, wv);
    stage_tile(Bp + kt * 64, Bs, tid, wv);
    __syncthreads();
    const __bf16* aB = As + (wm * 64 + lr) * 64;
    const __bf16* bB = Bs + (wn * 64 + lr) * 64;
#pragma unroll
    for (int ks = 0; ks < 2; ++ks) {
      const int xo = ((ks * 4 + lg) ^ x7) * 8;
      bf16x8 af[4], bf[4];
#pragma unroll
      for (int mi = 0; mi < 4; ++mi) af[mi] = *(const bf16x8*)(aB + mi * 16 * 64 + xo);
#pragma unroll
      for (int ni = 0; ni < 4; ++ni) bf[ni] = *(const bf16x8*)(bB + ni * 16 * 64 + xo);
#pragma unroll
      for (int mi = 0; mi < 4; ++mi)
#pragma unroll
        for (int ni = 0; ni < 4; ++ni)
          acc[mi][ni] = MFMA_(af[mi], bf[ni], acc[mi][ni]);
    }
    __syncthreads();
  }
}

// ---------------- task 0 + 4 shared experts (all A = x0): 6 GEMMs, fused combine ----
__global__ __launch_bounds__(256, 2) void task0_shared(const __bf16* __restrict__ xb0,
                                                       const __bf16* __restrict__ wT,
                                                       const float* __restrict__ shb,
                                                       const float* __restrict__ tkb,
                                                       const float* __restrict__ gates,
                                                       __bf16* __restrict__ shOut,
                                                       float* __restrict__ out) {
  __shared__ __align__(16) __bf16 As[128 * 64], Bs[128 * 64];
  const int rowBase = blockIdx.x * 128, colBase = blockIdx.y * 128;
  const int tid = threadIdx.x, lane = tid & 63, wv = tid >> 6;
  const int wm = wv >> 1, wn = wv & 1, lr = lane & 15, lg = lane >> 4;
  const __bf16* Ap = xb0 + (size_t)rowBase * KDIM;

  float outv[4][4][4];
#pragma unroll
  for (int mi = 0; mi < 4; ++mi)
#pragma unroll
    for (int ni = 0; ni < 4; ++ni)
#pragma unroll
      for (int r = 0; r < 4; ++r) outv[mi][ni][r] = 0.f;

#pragma unroll 1
  for (int e = 0; e < 6; ++e) {   // wT index e: shared 0..3, task0 experts 4,5
    f32x4 acc[4][4];
    f32x4 z = {0.f, 0.f, 0.f, 0.f};
#pragma unroll
    for (int mi = 0; mi < 4; ++mi)
#pragma unroll
      for (int ni = 0; ni < 4; ++ni) acc[mi][ni] = z;

    gemm_128(Ap, wT + ((size_t)e * ODIM + colBase) * KDIM, As, Bs, acc);

    const float* bias_p = (e < 4) ? (shb + e * ODIM) : (tkb + (e - 4) * ODIM);
#pragma unroll
    for (int ni = 0; ni < 4; ++ni) {
      int col = colBase + wn * 64 + ni * 16 + lr;
      float bias = bias_p[col];
#pragma unroll
      for (int mi = 0; mi < 4; ++mi)
#pragma unroll
        for (int r = 0; r < 4; ++r) {
          int row = rowBase + wm * 64 + mi * 16 + lg * 4 + r;
          float v = fmaxf(acc[mi][ni][r] + bias, 0.f);
          if (e < 4)
            shOut[((size_t)e * BROWS + row) * ODIM + col] = (__bf16)v;
          outv[mi][ni][r] += gates[(size_t)row * NGATE + e] * v;
        }
    }
  }

#pragma unroll
  for (int ni = 0; ni < 4; ++ni) {
    int col = colBase + wn * 64 + ni * 16 + lr;
#pragma unroll
    for (int mi = 0; mi < 4; ++mi)
#pragma unroll
      for (int r = 0; r < 4; ++r) {
        int row = rowBase + wm * 64 + mi * 16 + lg * 4 + r;
        out[(size_t)row * ODIM + col] = outv[mi][ni][r];
      }
  }
}

// ---------------- tasks 1,2: both experts paired in ONE K-loop + combine ----------
__global__ __launch_bounds__(256, 2) void task12_pair(const __bf16* __restrict__ xb,
                                                      const __bf16* __restrict__ wT,
                                                      const float* __restrict__ tkb,
                                                      const float* __restrict__ gates,
                                                      const __bf16* __restrict__ shOut,
                                                      float* __restrict__ out) {
  __shared__ __align__(16) __bf16 As[128 * 64], Bs0[128 * 64], Bs1[128 * 64];
  const int t = 1 + blockIdx.z;
  const int rowBase = blockIdx.x * 128, colBase = blockIdx.y * 128;
  const int tid = threadIdx.x, lane = tid & 63, wv = tid >> 6;
  const int wm = wv >> 1, wn = wv & 1, lr = lane & 15, lg = lane >> 4, x7 = lr & 7;
  const size_t NB = (size_t)BROWS * ODIM;

  const __bf16* Ap  = xb + ((size_t)t * BROWS + rowBase) * KDIM;
  const __bf16* Bp0 = wT + ((size_t)(4 + t * 2) * ODIM + colBase) * KDIM;
  const __bf16* Bp1 = wT + ((size_t)(4 + t * 2 + 1) * ODIM + colBase) * KDIM;

  f32x4 acc0[4][4], acc1[4][4];
  f32x4 z = {0.f, 0.f, 0.f, 0.f};
#pragma unroll
  for (int mi = 0; mi < 4; ++mi)
#pragma unroll
    for (int ni = 0; ni < 4; ++ni) { acc0[mi][ni] = z; acc1[mi][ni] = z; }

  for (int kt = 0; kt < 16; ++kt) {
    stage_tile(Ap  + kt * 64, As,  tid, wv);
    stage_tile(Bp0 + kt * 64, Bs0, tid, wv);
    stage_tile(Bp1 + kt * 64, Bs1, tid, wv);
    __syncthreads();
    const __bf16* aB  = As  + (wm * 64 + lr) * 64;
    const __bf16* bB0 = Bs0 + (wn * 64 + lr) * 64;
    const __bf16* bB1 = Bs1 + (wn * 64 + lr) * 64;
#pragma unroll
    for (int ks = 0; ks < 2; ++ks) {
      const int xo = ((ks * 4 + lg) ^ x7) * 8;
      bf16x8 af[4], bf0[4], bf1[4];
#pragma unroll
      for (int mi = 0; mi < 4; ++mi) af[mi]  = *(const bf16x8*)(aB  + mi * 16 * 64 + xo);
#pragma unroll
      for (int ni = 0; ni < 4; ++ni) bf0[ni] = *(const bf16x8*)(bB0 + ni * 16 * 64 + xo);
#pragma unroll
      for (int ni = 0; ni < 4; ++ni) bf1[ni] = *(const bf16x8*)(bB1 + ni * 16 * 64 + xo);
#pragma unroll
      for (int mi = 0; mi < 4; ++mi)
#pragma unroll
        for (int ni = 0; ni < 4; ++ni) {
          acc0[mi][ni] = MFMA_(af[mi], bf0[ni], acc0[mi][ni]);
          acc1[mi][ni] = MFMA_(af[mi], bf1[ni], acc1[mi][ni]);
        }
    }
    __syncthreads();
  }

#pragma unroll
  for (int mi = 0; mi < 4; ++mi)
#pragma unroll
    for (int r = 0; r < 4; ++r) {
      int row = rowBase + wm * 64 + mi * 16 + lg * 4 + r;
      const float* gp = gates + ((size_t)t * BROWS + row) * NGATE;
      float g0 = gp[0], g1 = gp[1], g2 = gp[2], g3 = gp[3], g4 = gp[4], g5 = gp[5];
#pragma unroll
      for (int ni = 0; ni < 4; ++ni) {
        int col = colBase + wn * 64 + ni * 16 + lr;
        size_t rc = (size_t)row * ODIM + col;
        float s = g0 * (float)shOut[rc] + g1 * (float)shOut[NB + rc] +
                  g2 * (float)shOut[2 * NB + rc] + g3 * (float)shOut[3 * NB + rc];
        s += g4 * fmaxf(acc0[mi][ni][r] + tkb[(t * 2) * ODIM + col], 0.f);
        s += g5 * fmaxf(acc1[mi][ni][r] + tkb[(t * 2 + 1) * ODIM + col], 0.f);
        out[((size_t)t * BROWS + row) * ODIM + col] = s;
      }
    }
}

extern "C" void kernel_launch(void* const* d_in, const int* in_sizes, int n_in,
                              void* d_out, int out_size, void* d_ws, size_t ws_size,
                              hipStream_t stream) {
  const float* x   = (const float*)d_in[0];
  const float* shW = (const float*)d_in[1];
  const float* shb = (const float*)d_in[2];
  const float* tkW = (const float*)d_in[3];
  const float* tkb = (const float*)d_in[4];
  const float* gW  = (const float*)d_in[5];
  const float* gb  = (const float*)d_in[6];
  float* out = (float*)d_out;
  (void)in_sizes; (void)n_in; (void)out_size; (void)ws_size;

  char* ws = (char*)d_ws;
  __bf16* xb    = (__bf16*)(ws + XB_OFF);
  __bf16* wT    = (__bf16*)(ws + WT_OFF);
  float*  gates = (float*) (ws + GT_OFF);
  __bf16* shOut = (__bf16*)(ws + SH_OFF);

  cvt_gates  <<<dim3((TTASKS * BROWS) / 4), 256, 0, stream>>>(x, xb, gW, gb, gates);
  cvt_weights<<<dim3(8, 16, 10), 256, 0, stream>>>(shW, tkW, wT);

  task0_shared<<<dim3(BROWS / 128, ODIM / 128), 256, 0, stream>>>(xb, wT, shb, tkb,
                                                                  gates, shOut, out);
  task12_pair <<<dim3(BROWS / 128, ODIM / 128, 2), 256, 0, stream>>>(xb, wT, tkb, gates,
                                                                     shOut, out);
}